// Round 10
// baseline (72.794 us; speedup 1.0000x reference)
//
#include <hip/hip_runtime.h>
#include <stdint.h>

#define BATCH 256
#define INF   1024
#define OUTF  128
#define KD    8
#define NN    1024      // OUTF*KD
#define OROW  1152      // INF + OUTF

#define MLS   12        // Mloc row stride in floats
#define CHB   16384     // bytes per x8 chunk: 256 rows x 64 B (K=64 fp8)
#define NBUF  8         // chunk buffers (7 in flight + 1 being read)
#define TP8   1056      // Tsl8 row pitch in bytes (1024 + 32: bank spread)

typedef __attribute__((ext_vector_type(4))) float f32x4;

// K1: T transpose-convert to fp8 (blocks 0..255) -> Tt8[n][k]; x copy + fp8
// convert (blocks 256..319). Same verified structure as the bf16 prep.
__global__ __launch_bounds__(256) void prep_kernel(
    const float* __restrict__ x, const float* __restrict__ T,
    float* __restrict__ out, unsigned char* __restrict__ x8,
    unsigned char* __restrict__ Tt8)
{
    __shared__ unsigned char lds8[64 * 68];   // [n][k] fp8, pitch 68 (17 dwords)
    int bid = blockIdx.x;
    int t = threadIdx.x;
    if (bid < 256) {
        int i0 = (bid >> 4) << 6;          // k-block
        int n0 = (bid & 15) << 6;          // n-block
        int tx = t & 63, ty = t >> 6;
        for (int r = ty; r < 64; r += 4) {
            float v = T[(size_t)(i0 + r) * NN + n0 + tx];
            lds8[tx * 68 + r] =
                (unsigned char)(__builtin_amdgcn_cvt_pk_fp8_f32(v, v, 0, false) & 0xff);
        }
        __syncthreads();
        #pragma unroll
        for (int p = 0; p < 4; ++p) {
            int q = p * 1024 + t * 4;
            int n = q >> 6, i = q & 63;    // i multiple of 4
            uint32_t w = *(const uint32_t*)(lds8 + n * 68 + i);
            *(uint32_t*)(Tt8 + (size_t)(n0 + n) * INF + i0 + i) = w;
        }
    } else {
        int bx = bid - 256;                // 0..63
        #pragma unroll
        for (int p = 0; p < 4; ++p) {
            int a = bx * 4 + p;
            int j = t * 4;
            float4 v = *(const float4*)(x + (size_t)a * INF + j);
            *(float4*)(out + (size_t)a * OROW + j) = v;
            uint32_t w = (uint32_t)__builtin_amdgcn_cvt_pk_fp8_f32(v.x, v.y, 0, false);
            w = (uint32_t)__builtin_amdgcn_cvt_pk_fp8_f32(v.z, v.w, (int)w, true);
            *(uint32_t*)(x8 + (size_t)a * INF + j) = w;
        }
    }
}

// DMA one 256x64B fp8 chunk of x8 into LDS. Wave w stages ONLY rows
// [32w,32w+32) (LDS bytes [2KB*w,2KB*(w+1))) and later reads only those rows:
// wave-private pipeline, no barrier. 16B-slot ^ (row&3) on the GLOBAL src
// (m173) so strided LDS reads are bank-spread.
__device__ __forceinline__ void stage_x8(
    const unsigned char* __restrict__ x8, unsigned char* lbuf,
    int c, int wave, int lane)
{
    const int r16 = lane >> 2;             // row within 16-row instr block
    const int slot = lane & 3;             // 16 B slot within 64 B row
    #pragma unroll
    for (int p = 0; p < 2; ++p) {
        const int i = wave * 2 + p;        // instr 0..15
        const unsigned char* src = x8 + (size_t)(i * 16 + r16) * INF
                                       + c * 64 + ((slot ^ (r16 & 3)) << 4);
        unsigned char* dst = lbuf + i * 1024;   // 1 KB per instr, linear
        __builtin_amdgcn_global_load_lds(
            (const __attribute__((address_space(1))) unsigned int*)src,
            (__attribute__((address_space(3))) unsigned int*)dst, 16, 0, 0);
    }
}

// One K=64 step: all LDS reads in ONE asm block (vmcnt gate + 6x ds_read_b64
// + lgkmcnt(0)) so hipcc inserts no vmcnt(0) drain (R7-proven structure).
// A-frag fp8 k-map: lane quad holds k = kb*32 + quad*8 .. +8 (8 bytes).
#define GEMM_STEP(c, VM) do {                                                 \
    const uint32_t bb = xlsBase + (uint32_t)(((c) & 7) * CHB);                \
    const uint32_t tb = tslBase + oB + (uint32_t)((c) << 6);                  \
    long long A00, A01, A10, A11, B0, B1;                                     \
    asm volatile(                                                             \
        "s_waitcnt vmcnt(" #VM ")\n\t"                                        \
        "ds_read_b64 %0, %6\n\t"                                              \
        "ds_read_b64 %1, %7\n\t"                                              \
        "ds_read_b64 %2, %8\n\t"                                              \
        "ds_read_b64 %3, %9\n\t"                                              \
        "ds_read_b64 %4, %10\n\t"                                             \
        "ds_read_b64 %5, %11\n\t"                                             \
        "s_waitcnt lgkmcnt(0)"                                                \
        : "=v"(A00), "=v"(A01), "=v"(A10), "=v"(A11), "=v"(B0), "=v"(B1)      \
        : "v"(bb + aA00), "v"(bb + aA01), "v"(bb + aA00 + 1024),              \
          "v"(bb + aA01 + 1024), "v"(tb), "v"(tb + 32)                        \
        : "memory");                                                          \
    acc0 = __builtin_amdgcn_mfma_f32_16x16x32_fp8_fp8(A00, B0, acc0, 0, 0, 0);\
    acc0 = __builtin_amdgcn_mfma_f32_16x16x32_fp8_fp8(A01, B1, acc0, 0, 0, 0);\
    acc1 = __builtin_amdgcn_mfma_f32_16x16x32_fp8_fp8(A10, B0, acc1, 0, 0, 0);\
    acc1 = __builtin_amdgcn_mfma_f32_16x16x32_fp8_fp8(A11, B1, acc1, 0, 0, 0);\
} while (0)

// K2: 256 blocks = (o, a-half). fp8 DMA-pipelined GEMM for M[:,o] (LDS-only),
// pair phase for this block's 128 a-rows, direct c write.
__global__ __launch_bounds__(512, 1) void fused_kernel(
    const unsigned char* __restrict__ x8, const unsigned char* __restrict__ Tt8,
    float* __restrict__ out)
{
    __shared__ __align__(16) unsigned char xls[NBUF * CHB];     // 128 KB
    __shared__ __align__(16) union {
        unsigned char Tsl[8 * TP8];                             // 8.25 KB (GEMM)
        float red[512];                                         // 2 KB (pair)
    } u;
    __shared__ __align__(16) float Mloc[256 * MLS];             // 12 KB
    // total 151808 B <= 160 KiB -> 1 block/CU

    const int o = blockIdx.x >> 1;
    const int half = blockIdx.x & 1;
    const int t = threadIdx.x;
    const int wave = t >> 6, lane = t & 63;

    // Stage Tsl: Tt8 row (o*8 + wave), 1 KB = 1 instr/wave, padded pitch.
    {
        const unsigned char* src = Tt8 + (size_t)(o * 8 + wave) * INF + lane * 16;
        unsigned char* dst = u.Tsl + wave * TP8;
        __builtin_amdgcn_global_load_lds(
            (const __attribute__((address_space(1))) unsigned int*)src,
            (__attribute__((address_space(3))) unsigned int*)dst, 16, 0, 0);
    }
    // Prologue: chunks 0..6 (depth-7; drained once by the entry barrier).
    #pragma unroll
    for (int c = 0; c < 7; ++c)
        stage_x8(x8, xls + c * CHB, c, wave, lane);
    __syncthreads();   // Tsl + chunks 0..6 landed; outstanding = 0

    // ---- GEMM: wave w owns M rows [32w,32w+32); 16 K-chunks ----
    const int rc = lane & 15, quad = lane >> 4;
    const int abase = wave * 32;
    f32x4 acc0 = {0.f, 0.f, 0.f, 0.f}, acc1 = {0.f, 0.f, 0.f, 0.f};

    const uint32_t xlsBase = (uint32_t)(uintptr_t)(&xls[0]);
    const uint32_t tslBase = (uint32_t)(uintptr_t)(&u.Tsl[0]);
    const uint32_t rowOff = (uint32_t)((abase + rc) * 64);
    // byte seg16 of k-byte (kb*32 + quad*8): kb*2 + (quad>>1), XOR-stored by row&3
    const uint32_t aA00 = rowOff
        + (uint32_t)(((((quad >> 1)) ^ (rc & 3)) << 4) + (quad & 1) * 8);
    const uint32_t aA01 = rowOff
        + (uint32_t)((((2 + (quad >> 1)) ^ (rc & 3)) << 4) + (quad & 1) * 8);
    const uint32_t oB = (uint32_t)((rc & 7) * TP8 + quad * 8);

    for (int c = 0; c < 9; ++c) {
        stage_x8(x8, xls + ((c + 7) & 7) * CHB, c + 7, wave, lane);
        GEMM_STEP(c, 14);              // 16 outstanding -> chunk c landed
    }
    GEMM_STEP(9, 12);
    GEMM_STEP(10, 10);
    GEMM_STEP(11, 8);
    GEMM_STEP(12, 6);
    GEMM_STEP(13, 4);
    GEMM_STEP(14, 2);
    GEMM_STEP(15, 0);

    // C/D layout: col = lane&15 (= kd, valid rc<8), row = quad*4 + r [m89/m91]
    if (rc < 8) {
        #pragma unroll
        for (int r = 0; r < 4; ++r) {
            Mloc[(abase + quad * 4 + r) * MLS + rc]      = acc0[r];
            Mloc[(abase + 16 + quad * 4 + r) * MLS + rc] = acc1[r];
        }
    }
    __syncthreads();   // Mloc ready; Tsl dead (union -> red)

    // ---- Pair phase: this block's 128 a-rows x all 256 b ----
    const int ar = t & 127;            // a-row within half
    const int bq = t >> 7;             // 0..3, wave-uniform -> LDS broadcast
    const int a = half * 128 + ar;
    f32x4 m0 = *(const f32x4*)(Mloc + a * MLS);
    f32x4 m1 = *(const f32x4*)(Mloc + a * MLS + 4);
    float ssum = 0.f;
    #pragma unroll 4
    for (int j = 0; j < 64; ++j) {
        const float* qp = Mloc + (bq * 64 + j) * MLS;
        f32x4 q0 = *(const f32x4*)(qp);
        f32x4 q1 = *(const f32x4*)(qp + 4);
        float d = fabsf(m0[0] - q0[0]) + fabsf(m0[1] - q0[1])
                + fabsf(m0[2] - q0[2]) + fabsf(m0[3] - q0[3])
                + fabsf(m1[0] - q1[0]) + fabsf(m1[1] - q1[1])
                + fabsf(m1[2] - q1[2]) + fabsf(m1[3] - q1[3]);
        ssum += __expf(-d);
    }
    u.red[t] = ssum;
    __syncthreads();
    if (t < 128) {
        float s = u.red[t] + u.red[t + 128] + u.red[t + 256] + u.red[t + 384];
        out[(size_t)(half * 128 + t) * OROW + INF + o] = s - 1.0f;  // -1 = self term
    }
}

extern "C" void kernel_launch(void* const* d_in, const int* in_sizes, int n_in,
                              void* d_out, int out_size, void* d_ws, size_t ws_size,
                              hipStream_t stream) {
    const float* x = (const float*)d_in[0];
    const float* T = (const float*)d_in[1];
    float* out = (float*)d_out;
    unsigned char* x8  = (unsigned char*)d_ws;                      // 256 KB
    unsigned char* Tt8 = (unsigned char*)d_ws + 262144;             // 1 MB

    prep_kernel<<<320, 256, 0, stream>>>(x, T, out, x8, Tt8);
    fused_kernel<<<256, 512, 0, stream>>>(x8, Tt8, out);
}

// Round 11
// 72.670 us; speedup vs baseline: 1.0017x; 1.0017x over previous
//
#include <hip/hip_runtime.h>
#include <stdint.h>

#define BATCH 256
#define INF   1024
#define OUTF  128
#define KD    8
#define NN    1024      // OUTF*KD
#define OROW  1152      // INF + OUTF

#define MLS   12        // Mloc row stride in floats
#define CHB   16384     // bytes per x8 chunk: 256 rows x 64 B (K=64 fp8)
#define NBUF  8         // chunk buffers (7 in flight + 1 being read)
#define TP8   1056      // Tsl8 row pitch in bytes (1024 + 32: bank spread)

typedef __attribute__((ext_vector_type(4))) float f32x4;

// K1 (R10-verified): T transpose-convert to fp8 (blocks 0..255) -> Tt8[n][k];
// x copy + fp8 convert (blocks 256..319).
__global__ __launch_bounds__(256) void prep_kernel(
    const float* __restrict__ x, const float* __restrict__ T,
    float* __restrict__ out, unsigned char* __restrict__ x8,
    unsigned char* __restrict__ Tt8)
{
    __shared__ unsigned char lds8[64 * 68];   // [n][k] fp8, pitch 68
    int bid = blockIdx.x;
    int t = threadIdx.x;
    if (bid < 256) {
        int i0 = (bid >> 4) << 6;          // k-block
        int n0 = (bid & 15) << 6;          // n-block
        int tx = t & 63, ty = t >> 6;
        for (int r = ty; r < 64; r += 4) {
            float v = T[(size_t)(i0 + r) * NN + n0 + tx];
            lds8[tx * 68 + r] =
                (unsigned char)(__builtin_amdgcn_cvt_pk_fp8_f32(v, v, 0, false) & 0xff);
        }
        __syncthreads();
        #pragma unroll
        for (int p = 0; p < 4; ++p) {
            int q = p * 1024 + t * 4;
            int n = q >> 6, i = q & 63;    // i multiple of 4
            uint32_t w = *(const uint32_t*)(lds8 + n * 68 + i);
            *(uint32_t*)(Tt8 + (size_t)(n0 + n) * INF + i0 + i) = w;
        }
    } else {
        int bx = bid - 256;                // 0..63
        #pragma unroll
        for (int p = 0; p < 4; ++p) {
            int a = bx * 4 + p;
            int j = t * 4;
            float4 v = *(const float4*)(x + (size_t)a * INF + j);
            *(float4*)(out + (size_t)a * OROW + j) = v;
            uint32_t w = (uint32_t)__builtin_amdgcn_cvt_pk_fp8_f32(v.x, v.y, 0, false);
            w = (uint32_t)__builtin_amdgcn_cvt_pk_fp8_f32(v.z, v.w, (int)w, true);
            *(uint32_t*)(x8 + (size_t)a * INF + j) = w;
        }
    }
}

// DMA this wave's 16 rows of chunk c (1 KB = ONE instr/wave). Wave w stages
// rows [16w,16w+16) -> LDS bytes [1KB*w,1KB*(w+1)) and later reads only those:
// wave-private pipeline, no barrier. 16B-slot ^ (row&3) on the GLOBAL src (m173).
__device__ __forceinline__ void stage1(
    const unsigned char* __restrict__ x8, unsigned char* lbuf,
    int c, int wave, int lane)
{
    const int r16 = lane >> 2;             // row within the wave's 16-row tile
    const int slot = lane & 3;             // 16 B slot within 64 B row
    const unsigned char* src = x8 + (size_t)(wave * 16 + r16) * INF
                                   + c * 64 + ((slot ^ (r16 & 3)) << 4);
    unsigned char* dst = lbuf + wave * 1024;
    __builtin_amdgcn_global_load_lds(
        (const __attribute__((address_space(1))) unsigned int*)src,
        (__attribute__((address_space(3))) unsigned int*)dst, 16, 0, 0);
}

// One K=64 step: all LDS reads in ONE asm block (vmcnt gate + 4x ds_read_b64
// + lgkmcnt(0)) so hipcc inserts no vmcnt(0) drain (R7-proven). The two MFMAs
// use INDEPENDENT accumulators (no intra-step dependent chain).
#define GEMM_STEP(c, VM) do {                                                 \
    const uint32_t bb = xlsBase + (uint32_t)(((c) & 7) * CHB);                \
    const uint32_t tb = tslBase + oB + (uint32_t)((c) << 6);                  \
    long long A00, A01, B0, B1;                                               \
    asm volatile(                                                             \
        "s_waitcnt vmcnt(" #VM ")\n\t"                                        \
        "ds_read_b64 %0, %4\n\t"                                              \
        "ds_read_b64 %1, %5\n\t"                                              \
        "ds_read_b64 %2, %6\n\t"                                              \
        "ds_read_b64 %3, %7\n\t"                                              \
        "s_waitcnt lgkmcnt(0)"                                                \
        : "=v"(A00), "=v"(A01), "=v"(B0), "=v"(B1)                            \
        : "v"(bb + aA00), "v"(bb + aA01), "v"(tb), "v"(tb + 32)               \
        : "memory");                                                          \
    accE = __builtin_amdgcn_mfma_f32_16x16x32_fp8_fp8(A00, B0, accE, 0, 0, 0);\
    accO = __builtin_amdgcn_mfma_f32_16x16x32_fp8_fp8(A01, B1, accO, 0, 0, 0);\
} while (0)

// K2: 256 blocks = (o, a-half), 1024 threads = 16 waves (4/SIMD: TLP hides the
// per-step LDS/MFMA latency chain). Wave w owns M rows [16w,16w+16).
__global__ __launch_bounds__(1024, 1) void fused_kernel(
    const unsigned char* __restrict__ x8, const unsigned char* __restrict__ Tt8,
    float* __restrict__ out)
{
    __shared__ __align__(16) unsigned char xls[NBUF * CHB];     // 128 KB
    __shared__ __align__(16) union {
        unsigned char Tsl[8 * TP8];                             // 8.25 KB (GEMM)
        float red[1024];                                        // 4 KB (pair)
    } u;
    __shared__ __align__(16) float Mloc[256 * MLS];             // 12 KB
    // total 151808 B <= 160 KiB -> 1 block/CU

    const int o = blockIdx.x >> 1;
    const int half = blockIdx.x & 1;
    const int t = threadIdx.x;
    const int wave = t >> 6, lane = t & 63;

    // Stage Tsl: waves 0..7 load Tt8 row (o*8 + wave), 1 KB each, padded pitch.
    if (wave < 8) {
        const unsigned char* src = Tt8 + (size_t)(o * 8 + wave) * INF + lane * 16;
        unsigned char* dst = u.Tsl + wave * TP8;
        __builtin_amdgcn_global_load_lds(
            (const __attribute__((address_space(1))) unsigned int*)src,
            (__attribute__((address_space(3))) unsigned int*)dst, 16, 0, 0);
    }
    // Prologue: chunks 0..6 (depth-7; drained once by the entry barrier).
    #pragma unroll
    for (int c = 0; c < 7; ++c)
        stage1(x8, xls + c * CHB, c, wave, lane);
    __syncthreads();   // Tsl + chunks 0..6 landed; outstanding = 0 per wave

    // ---- GEMM: 16 K-chunks, 1 DMA instr/wave/chunk, depth-7 ----
    const int rc = lane & 15, quad = lane >> 4;
    f32x4 accE = {0.f, 0.f, 0.f, 0.f}, accO = {0.f, 0.f, 0.f, 0.f};

    const uint32_t xlsBase = (uint32_t)(uintptr_t)(&xls[0]);
    const uint32_t tslBase = (uint32_t)(uintptr_t)(&u.Tsl[0]);
    const uint32_t rowOff = (uint32_t)((wave * 16 + rc) * 64);
    // k-byte (kb*32 + quad*8) -> 16B slot (kb*2 + (quad>>1)) ^ (row&3), +8 if quad odd
    const uint32_t aA00 = rowOff
        + (uint32_t)(((((quad >> 1)) ^ (rc & 3)) << 4) + (quad & 1) * 8);
    const uint32_t aA01 = rowOff
        + (uint32_t)((((2 + (quad >> 1)) ^ (rc & 3)) << 4) + (quad & 1) * 8);
    const uint32_t oB = (uint32_t)((rc & 7) * TP8 + quad * 8);

    for (int c = 0; c < 9; ++c) {
        stage1(x8, xls + ((c + 7) & 7) * CHB, c + 7, wave, lane);
        GEMM_STEP(c, 7);               // 8 outstanding -> chunk c landed
    }
    GEMM_STEP(9, 6);
    GEMM_STEP(10, 5);
    GEMM_STEP(11, 4);
    GEMM_STEP(12, 3);
    GEMM_STEP(13, 2);
    GEMM_STEP(14, 1);
    GEMM_STEP(15, 0);

    // C/D layout: col = lane&15 (= kd, valid rc<8), row = quad*4 + r [m89/m91]
    if (rc < 8) {
        #pragma unroll
        for (int r = 0; r < 4; ++r)
            Mloc[(wave * 16 + quad * 4 + r) * MLS + rc] = accE[r] + accO[r];
    }
    __syncthreads();   // Mloc ready; Tsl dead (union -> red)

    // ---- Pair phase: this block's 128 a-rows x all 256 b (8-way b-split) ----
    const int ar = t & 127;            // a-row within half
    const int bq = t >> 7;             // 0..7, wave-uniform -> LDS broadcast
    const int a = half * 128 + ar;
    f32x4 m0 = *(const f32x4*)(Mloc + a * MLS);
    f32x4 m1 = *(const f32x4*)(Mloc + a * MLS + 4);
    float ssum = 0.f;
    #pragma unroll 4
    for (int j = 0; j < 32; ++j) {
        const float* qp = Mloc + (bq * 32 + j) * MLS;
        f32x4 q0 = *(const f32x4*)(qp);
        f32x4 q1 = *(const f32x4*)(qp + 4);
        float d = fabsf(m0[0] - q0[0]) + fabsf(m0[1] - q0[1])
                + fabsf(m0[2] - q0[2]) + fabsf(m0[3] - q0[3])
                + fabsf(m1[0] - q1[0]) + fabsf(m1[1] - q1[1])
                + fabsf(m1[2] - q1[2]) + fabsf(m1[3] - q1[3]);
        ssum += __expf(-d);
    }
    u.red[t] = ssum;
    __syncthreads();
    if (t < 128) {
        float s = 0.f;
        #pragma unroll
        for (int q = 0; q < 8; ++q) s += u.red[t + q * 128];
        out[(size_t)(half * 128 + t) * OROW + INF + o] = s - 1.0f;  // -1 = self term
    }
}

extern "C" void kernel_launch(void* const* d_in, const int* in_sizes, int n_in,
                              void* d_out, int out_size, void* d_ws, size_t ws_size,
                              hipStream_t stream) {
    const float* x = (const float*)d_in[0];
    const float* T = (const float*)d_in[1];
    float* out = (float*)d_out;
    unsigned char* x8  = (unsigned char*)d_ws;                      // 256 KB
    unsigned char* Tt8 = (unsigned char*)d_ws + 262144;             // 1 MB

    prep_kernel<<<320, 256, 0, stream>>>(x, T, out, x8, Tt8);
    fused_kernel<<<256, 1024, 0, stream>>>(x8, Tt8, out);
}

// Round 12
// 72.114 us; speedup vs baseline: 1.0094x; 1.0077x over previous
//
#include <hip/hip_runtime.h>
#include <stdint.h>

#define BATCH 256
#define INF   1024
#define OUTF  128
#define KD    8
#define NN    1024      // OUTF*KD
#define OROW  1152      // INF + OUTF

#define MLS   12        // Mloc row stride in floats
#define CHB   32768     // bytes per x8 chunk: 256 rows x 128 B (K=128 fp8)
#define NBUF  4         // chunk buffers (3 in flight + 1 being read)
#define TP8   1056      // Tsl8 row pitch in bytes (1024 + 32: bank spread)

typedef __attribute__((ext_vector_type(4))) float f32x4;

// K1 (R10-verified, unchanged): T transpose-convert to fp8 -> Tt8[n][k]
// (blocks 0..255); x copy + fp8 convert (blocks 256..319).
__global__ __launch_bounds__(256) void prep_kernel(
    const float* __restrict__ x, const float* __restrict__ T,
    float* __restrict__ out, unsigned char* __restrict__ x8,
    unsigned char* __restrict__ Tt8)
{
    __shared__ unsigned char lds8[64 * 68];   // [n][k] fp8, pitch 68
    int bid = blockIdx.x;
    int t = threadIdx.x;
    if (bid < 256) {
        int i0 = (bid >> 4) << 6;          // k-block
        int n0 = (bid & 15) << 6;          // n-block
        int tx = t & 63, ty = t >> 6;
        for (int r = ty; r < 64; r += 4) {
            float v = T[(size_t)(i0 + r) * NN + n0 + tx];
            lds8[tx * 68 + r] =
                (unsigned char)(__builtin_amdgcn_cvt_pk_fp8_f32(v, v, 0, false) & 0xff);
        }
        __syncthreads();
        #pragma unroll
        for (int p = 0; p < 4; ++p) {
            int q = p * 1024 + t * 4;
            int n = q >> 6, i = q & 63;    // i multiple of 4
            uint32_t w = *(const uint32_t*)(lds8 + n * 68 + i);
            *(uint32_t*)(Tt8 + (size_t)(n0 + n) * INF + i0 + i) = w;
        }
    } else {
        int bx = bid - 256;                // 0..63
        #pragma unroll
        for (int p = 0; p < 4; ++p) {
            int a = bx * 4 + p;
            int j = t * 4;
            float4 v = *(const float4*)(x + (size_t)a * INF + j);
            *(float4*)(out + (size_t)a * OROW + j) = v;
            uint32_t w = (uint32_t)__builtin_amdgcn_cvt_pk_fp8_f32(v.x, v.y, 0, false);
            w = (uint32_t)__builtin_amdgcn_cvt_pk_fp8_f32(v.z, v.w, (int)w, true);
            *(uint32_t*)(x8 + (size_t)a * INF + j) = w;
        }
    }
}

// DMA this wave's 32 rows of one 256x128B fp8 chunk (4 instrs/wave).
// Global row g lands at slab offset g*128 (linear); 16B-slot ^ (row&7) applied
// on the GLOBAL source (m173) so swizzled reads are bank-spread. Wave-private:
// wave w stages rows [32w,32w+32) and reads only those -> no barrier needed.
__device__ __forceinline__ void stage1(
    const unsigned char* __restrict__ x8, unsigned char* lbuf,
    int c, int wave, int lane)
{
    const int rin = lane >> 3;             // row within 8-row instr block
    const int slot = lane & 7;             // 16 B slot within 128 B row
    #pragma unroll
    for (int p = 0; p < 4; ++p) {
        const int row = wave * 32 + p * 8 + rin;
        const unsigned char* src = x8 + (size_t)row * INF
                                       + c * 128 + ((slot ^ rin) << 4);
        unsigned char* dst = lbuf + wave * 4096 + p * 1024;
        __builtin_amdgcn_global_load_lds(
            (const __attribute__((address_space(1))) unsigned int*)src,
            (__attribute__((address_space(3))) unsigned int*)dst, 16, 0, 0);
    }
}

// One K=128 step: vmcnt gate + 12x ds_read_b64 + lgkmcnt(0) in ONE asm block
// (hipcc sees no C-level LDS read -> no vmcnt(0) drain; R7-proven). 4 accs,
// max MFMA dependence chain = 2 per chunk.
#define GEMM_STEP(c, VM) do {                                                 \
    const uint32_t bb = xlsBase + (uint32_t)(((c) & 3) * CHB);                \
    const uint32_t tb = tslBase + oB + (uint32_t)((c) << 7);                  \
    long long A00, A01, A02, A03, A10, A11, A12, A13, B0, B1, B2, B3;         \
    asm volatile(                                                             \
        "s_waitcnt vmcnt(" #VM ")\n\t"                                        \
        "ds_read_b64 %0, %12\n\t"                                             \
        "ds_read_b64 %1, %13\n\t"                                             \
        "ds_read_b64 %2, %14\n\t"                                             \
        "ds_read_b64 %3, %15\n\t"                                             \
        "ds_read_b64 %4, %16\n\t"                                             \
        "ds_read_b64 %5, %17\n\t"                                             \
        "ds_read_b64 %6, %18\n\t"                                             \
        "ds_read_b64 %7, %19\n\t"                                             \
        "ds_read_b64 %8, %20\n\t"                                             \
        "ds_read_b64 %9, %21\n\t"                                             \
        "ds_read_b64 %10, %22\n\t"                                            \
        "ds_read_b64 %11, %23\n\t"                                            \
        "s_waitcnt lgkmcnt(0)"                                                \
        : "=&v"(A00), "=&v"(A01), "=&v"(A02), "=&v"(A03),                     \
          "=&v"(A10), "=&v"(A11), "=&v"(A12), "=&v"(A13),                     \
          "=&v"(B0), "=&v"(B1), "=&v"(B2), "=&v"(B3)                          \
        : "v"(bb + aL0), "v"(bb + aL1), "v"(bb + aL2), "v"(bb + aL3),         \
          "v"(bb + aL0 + 2048), "v"(bb + aL1 + 2048),                         \
          "v"(bb + aL2 + 2048), "v"(bb + aL3 + 2048),                         \
          "v"(tb), "v"(tb + 32), "v"(tb + 64), "v"(tb + 96)                   \
        : "memory");                                                          \
    accL0 = __builtin_amdgcn_mfma_f32_16x16x32_fp8_fp8(A00, B0, accL0, 0, 0, 0);\
    accH0 = __builtin_amdgcn_mfma_f32_16x16x32_fp8_fp8(A10, B0, accH0, 0, 0, 0);\
    accL1 = __builtin_amdgcn_mfma_f32_16x16x32_fp8_fp8(A01, B1, accL1, 0, 0, 0);\
    accH1 = __builtin_amdgcn_mfma_f32_16x16x32_fp8_fp8(A11, B1, accH1, 0, 0, 0);\
    accL0 = __builtin_amdgcn_mfma_f32_16x16x32_fp8_fp8(A02, B2, accL0, 0, 0, 0);\
    accH0 = __builtin_amdgcn_mfma_f32_16x16x32_fp8_fp8(A12, B2, accH0, 0, 0, 0);\
    accL1 = __builtin_amdgcn_mfma_f32_16x16x32_fp8_fp8(A03, B3, accL1, 0, 0, 0);\
    accH1 = __builtin_amdgcn_mfma_f32_16x16x32_fp8_fp8(A13, B3, accH1, 0, 0, 0);\
} while (0)

// K2: 256 blocks = (o, a-half), 512 threads = 8 waves; wave w owns M rows
// [32w,32w+32). 8 K-chunks of K=128, depth-3 wave-private DMA pipeline.
__global__ __launch_bounds__(512, 1) void fused_kernel(
    const unsigned char* __restrict__ x8, const unsigned char* __restrict__ Tt8,
    float* __restrict__ out)
{
    __shared__ __align__(16) unsigned char xls[NBUF * CHB];     // 128 KB
    __shared__ __align__(16) union {
        unsigned char Tsl[8 * TP8];                             // 8.25 KB (GEMM)
        float red[512];                                         // 2 KB (pair)
    } u;
    __shared__ __align__(16) float Mloc[256 * MLS];             // 12 KB
    // total 151808 B <= 160 KiB -> 1 block/CU

    const int o = blockIdx.x >> 1;
    const int half = blockIdx.x & 1;
    const int t = threadIdx.x;
    const int wave = t >> 6, lane = t & 63;

    // Stage Tsl: wave w loads Tt8 row (o*8 + w), 1 KB, padded pitch.
    {
        const unsigned char* src = Tt8 + (size_t)(o * 8 + wave) * INF + lane * 16;
        unsigned char* dst = u.Tsl + wave * TP8;
        __builtin_amdgcn_global_load_lds(
            (const __attribute__((address_space(1))) unsigned int*)src,
            (__attribute__((address_space(3))) unsigned int*)dst, 16, 0, 0);
    }
    // Prologue: chunks 0..2 (depth-3; drained once by the entry barrier).
    stage1(x8, xls + 0 * CHB, 0, wave, lane);
    stage1(x8, xls + 1 * CHB, 1, wave, lane);
    stage1(x8, xls + 2 * CHB, 2, wave, lane);
    __syncthreads();   // Tsl + chunks 0..2 landed; outstanding = 0

    // ---- GEMM: 8 K-chunks (K=128 each) ----
    const int rc = lane & 15, quad = lane >> 4;
    const int abase = wave * 32;
    f32x4 accL0 = {0.f,0.f,0.f,0.f}, accL1 = {0.f,0.f,0.f,0.f};
    f32x4 accH0 = {0.f,0.f,0.f,0.f}, accH1 = {0.f,0.f,0.f,0.f};

    const uint32_t xlsBase = (uint32_t)(uintptr_t)(&xls[0]);
    const uint32_t tslBase = (uint32_t)(uintptr_t)(&u.Tsl[0]);
    const uint32_t rowOff = (uint32_t)((abase + rc) * 128);
    // k-byte (ksub*32 + quad*8) -> slot (ksub*2 + (quad>>1)) ^ (row&7), +8 if quad odd
    const uint32_t qlo = (uint32_t)((quad & 1) * 8);
    const uint32_t aL0 = rowOff + ((((0u * 2 + (quad >> 1)) ^ (rc & 7)) << 4) + qlo);
    const uint32_t aL1 = rowOff + ((((1u * 2 + (quad >> 1)) ^ (rc & 7)) << 4) + qlo);
    const uint32_t aL2 = rowOff + ((((2u * 2 + (quad >> 1)) ^ (rc & 7)) << 4) + qlo);
    const uint32_t aL3 = rowOff + ((((3u * 2 + (quad >> 1)) ^ (rc & 7)) << 4) + qlo);
    const uint32_t oB = (uint32_t)((rc & 7) * TP8 + quad * 8);

    for (int c = 0; c < 5; ++c) {
        stage1(x8, xls + ((c + 3) & 3) * CHB, c + 3, wave, lane);
        GEMM_STEP(c, 12);              // chunks c+1..c+3 in flight (12 instrs)
    }
    GEMM_STEP(5, 8);
    GEMM_STEP(6, 4);
    GEMM_STEP(7, 0);

    // C/D layout: col = lane&15 (= kd, valid rc<8), row = quad*4 + r [m89/m91]
    if (rc < 8) {
        #pragma unroll
        for (int r = 0; r < 4; ++r) {
            Mloc[(abase + quad * 4 + r) * MLS + rc]      = accL0[r] + accL1[r];
            Mloc[(abase + 16 + quad * 4 + r) * MLS + rc] = accH0[r] + accH1[r];
        }
    }
    __syncthreads();   // Mloc ready; Tsl dead (union -> red)

    // ---- Pair phase: this block's 128 a-rows x all 256 b (4-way b-split) ----
    const int ar = t & 127;            // a-row within half
    const int bq = t >> 7;             // 0..3, wave-uniform -> LDS broadcast
    const int a = half * 128 + ar;
    f32x4 m0 = *(const f32x4*)(Mloc + a * MLS);
    f32x4 m1 = *(const f32x4*)(Mloc + a * MLS + 4);
    float ssum = 0.f;
    #pragma unroll 4
    for (int j = 0; j < 64; ++j) {
        const float* qp = Mloc + (bq * 64 + j) * MLS;
        f32x4 q0 = *(const f32x4*)(qp);
        f32x4 q1 = *(const f32x4*)(qp + 4);
        float d = fabsf(m0[0] - q0[0]) + fabsf(m0[1] - q0[1])
                + fabsf(m0[2] - q0[2]) + fabsf(m0[3] - q0[3])
                + fabsf(m1[0] - q1[0]) + fabsf(m1[1] - q1[1])
                + fabsf(m1[2] - q1[2]) + fabsf(m1[3] - q1[3]);
        ssum += __expf(-d);
    }
    u.red[t] = ssum;
    __syncthreads();
    if (t < 128) {
        float s = u.red[t] + u.red[t + 128] + u.red[t + 256] + u.red[t + 384];
        out[(size_t)(half * 128 + t) * OROW + INF + o] = s - 1.0f;  // -1 = self term
    }
}

extern "C" void kernel_launch(void* const* d_in, const int* in_sizes, int n_in,
                              void* d_out, int out_size, void* d_ws, size_t ws_size,
                              hipStream_t stream) {
    const float* x = (const float*)d_in[0];
    const float* T = (const float*)d_in[1];
    float* out = (float*)d_out;
    unsigned char* x8  = (unsigned char*)d_ws;                      // 256 KB
    unsigned char* Tt8 = (unsigned char*)d_ws + 262144;             // 1 MB

    prep_kernel<<<320, 256, 0, stream>>>(x, T, out, x8, Tt8);
    fused_kernel<<<256, 512, 0, stream>>>(x8, Tt8, out);
}